// Round 4
// baseline (113.534 us; speedup 1.0000x reference)
//
#include <hip/hip_runtime.h>
#include <hip/hip_cooperative_groups.h>
#include <math.h>

namespace cg = cooperative_groups;

#define B_ 8
#define N_ 128
#define M_ 256
#define F_ 256

#define LOG2E2 2.8853900817779268f  // 2*log2(e)
#define YF 64                       // y f-chunk staged in LDS
#define YPAD 4

// ---------------------------------------------------------------------------
// One cooperative kernel, 256 blocks x 512 threads (1 block/CU).
// Block (b = bid>>5, nc = bid&31) owns n rows n0..n0+3 and ALL 256 m.
//
// Phase A1: recompute u[n0..n0+3][0..255] locally (no global u buffer):
//           u[r][g] = (x[r,:].Uw[g,:] + Ub[g]) * 2log2e   -> LDS us[4][256]
//           (x row reads are wave-uniform -> scalar cache; Uw read coalesced
//            per-lane g, 256 KB/block from L2)
// Phase A2: alpha[n,m] = Wsum - 2*sum_f Ww[f]*rcp(exp2(us[n][f]*y[m][f])+1)
//           (tanh identity; W_b dropped: max/softmax shift-invariant)
//           row-max over all m -> rowmax[B][N] (final)
//           col-max over 4 n   -> cpart[B][32][M] (partial)
// grid sync
// Phase B (8 blocks): two softmaxes + pooled dots -> out[B][512]
// ---------------------------------------------------------------------------
__global__ __launch_bounds__(512, 2) void fused_all(
    const float* __restrict__ x, const float* __restrict__ y,
    const float* __restrict__ Uw, const float* __restrict__ Ub,
    const float* __restrict__ Ww,
    float* __restrict__ rowmax, float* __restrict__ cpart,
    float* __restrict__ out) {
  __shared__ float ys[M_][YF + YPAD];   // 68 KB
  __shared__ float us[4][F_];           // 4 KB
  __shared__ float wl[F_];              // 1 KB
  __shared__ float cm[2][M_];           // 2 KB
  __shared__ float rm[8][2];
  __shared__ float red[8];
  __shared__ float xw[N_];
  __shared__ float yw[M_];
  __shared__ float part[2][256];

  const int tid = threadIdx.x;
  const int bid = blockIdx.x;
  const int b   = bid >> 5;
  const int nc  = bid & 31;
  const int n0  = nc * 4;
  const int m   = tid & 255;
  const int w   = tid >> 6;                                 // wave 0..7
  const int ng  = __builtin_amdgcn_readfirstlane(w >> 2);   // 0..1 wave-uniform

  // ---------- Phase A1: local u rows ----------
  if (tid < 256) {
    const int g = tid;
    const float* __restrict__ uwr = Uw + (size_t)g * F_;
    const float* __restrict__ xr  = x + (size_t)(b * N_ + n0) * F_;  // uniform
    float a0 = 0.f, a1 = 0.f, a2 = 0.f, a3 = 0.f;
#pragma unroll 4
    for (int f = 0; f < F_; f += 4) {
      const float4 wv = *(const float4*)&uwr[f];           // per-lane
      const float4 x0 = *(const float4*)&xr[0 * F_ + f];   // uniform -> s_load
      const float4 x1 = *(const float4*)&xr[1 * F_ + f];
      const float4 x2 = *(const float4*)&xr[2 * F_ + f];
      const float4 x3 = *(const float4*)&xr[3 * F_ + f];
      a0 = fmaf(wv.x, x0.x, a0); a0 = fmaf(wv.y, x0.y, a0);
      a0 = fmaf(wv.z, x0.z, a0); a0 = fmaf(wv.w, x0.w, a0);
      a1 = fmaf(wv.x, x1.x, a1); a1 = fmaf(wv.y, x1.y, a1);
      a1 = fmaf(wv.z, x1.z, a1); a1 = fmaf(wv.w, x1.w, a1);
      a2 = fmaf(wv.x, x2.x, a2); a2 = fmaf(wv.y, x2.y, a2);
      a2 = fmaf(wv.z, x2.z, a2); a2 = fmaf(wv.w, x2.w, a2);
      a3 = fmaf(wv.x, x3.x, a3); a3 = fmaf(wv.y, x3.y, a3);
      a3 = fmaf(wv.z, x3.z, a3); a3 = fmaf(wv.w, x3.w, a3);
    }
    const float ub = Ub[g];
    us[0][g] = (a0 + ub) * LOG2E2;
    us[1][g] = (a1 + ub) * LOG2E2;
    us[2][g] = (a2 + ub) * LOG2E2;
    us[3][g] = (a3 + ub) * LOG2E2;
  } else if (tid < 320) {
    const int c = (tid - 256) * 4;
    *(float4*)&wl[c] = *(const float4*)&Ww[c];
  }

  // ---------- Phase A2: alpha + tile reductions ----------
  float acc0 = 0.f, acc1 = 0.f, wsum = 0.f;

  for (int f0 = 0; f0 < F_; f0 += YF) {
    __syncthreads();   // covers A1 stores before first chunk, ys reuse after
#pragma unroll
    for (int k = 0; k < 8; ++k) {
      const int i = tid + k * 512;
      const int ms = i >> 4, c = (i & 15) * 4;
      const float4 v = *(const float4*)&y[(size_t)(b * M_ + ms) * F_ + f0 + c];
      *(float4*)&ys[ms][c] = v;
    }
    __syncthreads();

    for (int fg = 0; fg < YF; fg += 4) {
      const float4 yv = *(const float4*)&ys[m][fg];               // per-lane
      const float4 ua = *(const float4*)&us[ng * 2 + 0][f0 + fg]; // broadcast
      const float4 ub4 = *(const float4*)&us[ng * 2 + 1][f0 + fg];
      const float4 wv = *(const float4*)&wl[f0 + fg];
      const float* yp = (const float*)&yv;
      const float* ap = (const float*)&ua;
      const float* bp = (const float*)&ub4;
      const float* wp = (const float*)&wv;
      wsum += wp[0] + wp[1] + wp[2] + wp[3];
#pragma unroll
      for (int j = 0; j < 4; ++j) {
        const float yj = yp[j];
        const float e0 = __builtin_amdgcn_exp2f(ap[j] * yj);
        const float e1 = __builtin_amdgcn_exp2f(bp[j] * yj);
        acc0 = fmaf(wp[j], __builtin_amdgcn_rcpf(e0 + 1.f), acc0);
        acc1 = fmaf(wp[j], __builtin_amdgcn_rcpf(e1 + 1.f), acc1);
      }
    }
  }

  const float alpha0 = wsum - 2.f * acc0;   // (n0+2ng,   m)
  const float alpha1 = wsum - 2.f * acc1;   // (n0+2ng+1, m)

  float r0 = alpha0, r1 = alpha1;
#pragma unroll
  for (int s = 32; s; s >>= 1) {
    r0 = fmaxf(r0, __shfl_xor(r0, s));
    r1 = fmaxf(r1, __shfl_xor(r1, s));
  }
  if ((tid & 63) == 0) { rm[w][0] = r0; rm[w][1] = r1; }
  cm[ng][m] = fmaxf(alpha0, alpha1);
  __syncthreads();
  if (tid < 4) {
    const int g = tid >> 1, j = tid & 1;
    float v = rm[g * 4][j];
#pragma unroll
    for (int k = 1; k < 4; ++k) v = fmaxf(v, rm[g * 4 + k][j]);
    rowmax[b * N_ + n0 + 2 * g + j] = v;
  }
  if (tid < 256)
    cpart[((size_t)b * 32 + nc) * M_ + tid] = fmaxf(cm[0][tid], cm[1][tid]);

  __threadfence();          // device-scope release of rowmax/cpart
  cg::this_grid().sync();
  if (nc != 0) return;

  // ---------- Phase B: per-batch finish (8 blocks, 512 threads) ----------
  __threadfence();          // acquire side

  // x attention: softmax over n of rowmax
  const float rv = (tid < N_) ? rowmax[b * N_ + tid] : -INFINITY;
  float m1 = rv;
#pragma unroll
  for (int s = 32; s; s >>= 1) m1 = fmaxf(m1, __shfl_xor(m1, s));
  if ((tid & 63) == 0) red[w] = m1;
  __syncthreads();
  m1 = red[0];
#pragma unroll
  for (int k = 1; k < 8; ++k) m1 = fmaxf(m1, red[k]);
  __syncthreads();
  const float e1 = (tid < N_) ? __expf(rv - m1) : 0.f;
  float s1 = e1;
#pragma unroll
  for (int s = 32; s; s >>= 1) s1 += __shfl_xor(s1, s);
  if ((tid & 63) == 0) red[w] = s1;
  __syncthreads();
  s1 = red[0] + red[1] + red[2] + red[3] + red[4] + red[5] + red[6] + red[7];
  if (tid < N_) xw[tid] = e1 / s1;
  __syncthreads();

  // y attention: softmax over m of colmax (reduce 32 partials)
  float cv = -INFINITY;
  if (tid < M_) {
#pragma unroll 8
    for (int k = 0; k < 32; ++k)
      cv = fmaxf(cv, cpart[((size_t)b * 32 + k) * M_ + tid]);
  }
  float m2 = cv;
#pragma unroll
  for (int s = 32; s; s >>= 1) m2 = fmaxf(m2, __shfl_xor(m2, s));
  if ((tid & 63) == 0) red[w] = m2;
  __syncthreads();
  m2 = red[0];
#pragma unroll
  for (int k = 1; k < 8; ++k) m2 = fmaxf(m2, red[k]);
  __syncthreads();
  const float e2 = (tid < M_) ? __expf(cv - m2) : 0.f;
  float s2 = e2;
#pragma unroll
  for (int s = 32; s; s >>= 1) s2 += __shfl_xor(s2, s);
  if ((tid & 63) == 0) red[w] = s2;
  __syncthreads();
  s2 = red[0] + red[1] + red[2] + red[3] + red[4] + red[5] + red[6] + red[7];
  if (tid < M_) yw[tid] = e2 / s2;
  __syncthreads();

  // pooled outputs, 2-way split over sum dimension
  const int q = tid >> 8;   // 0..1
  const int f = tid & 255;
  float accx = 0.f;
#pragma unroll 4
  for (int n = q; n < N_; n += 2)
    accx = fmaf(xw[n], x[(size_t)(b * N_ + n) * F_ + f], accx);
  part[q][f] = accx;
  __syncthreads();
  if (tid < 256) out[b * (2 * F_) + f] = part[0][f] + part[1][f];
  __syncthreads();
  float accy = 0.f;
#pragma unroll 4
  for (int mm = q; mm < M_; mm += 2)
    accy = fmaf(yw[mm], y[(size_t)(b * M_ + mm) * F_ + f], accy);
  part[q][f] = accy;
  __syncthreads();
  if (tid < 256) out[b * (2 * F_) + F_ + f] = part[0][f] + part[1][f];
}

// ---------------------------------------------------------------------------
extern "C" void kernel_launch(void* const* d_in, const int* in_sizes, int n_in,
                              void* d_out, int out_size, void* d_ws, size_t ws_size,
                              hipStream_t stream) {
  (void)in_sizes; (void)n_in; (void)out_size; (void)ws_size;
  const float* x  = (const float*)d_in[0];
  const float* y  = (const float*)d_in[1];
  const float* Uw = (const float*)d_in[2];
  const float* Ub = (const float*)d_in[3];
  const float* Ww = (const float*)d_in[4];
  // d_in[5] (W_b) unused: max/softmax pipeline is shift-invariant.

  float* rowmax = (float*)d_ws;            // [B][N]       1024 f
  float* cpart  = rowmax + B_ * N_;        // [B][32][M]  65536 f
  float* outp   = (float*)d_out;

  void* kargs[] = {(void*)&x, (void*)&y, (void*)&Uw, (void*)&Ub, (void*)&Ww,
                   (void*)&rowmax, (void*)&cpart, (void*)&outp};
  hipLaunchCooperativeKernel((void*)fused_all, dim3(256), dim3(512), kargs, 0,
                             stream);
}

// Round 5
// 51.359 us; speedup vs baseline: 2.2106x; 2.2106x over previous
//
#include <hip/hip_runtime.h>
#include <math.h>

#define B_ 8
#define N_ 128
#define M_ 256
#define F_ 256

#define LOG2E2 2.8853900817779268f  // 2*log2(e)

// ---------------------------------------------------------------------------
// K1: u[r][g] = (x[r,:] . Uw[g,:] + Ub[g]) * 2log2e       r = b*N+n (1024 rows)
// ---------------------------------------------------------------------------
#define K1_BM 32
#define K1_BN 64
#define K1_BK 32

__global__ __launch_bounds__(256) void k1_gemm(const float* __restrict__ x,
                                               const float* __restrict__ Uw,
                                               const float* __restrict__ Ub,
                                               float* __restrict__ u) {
  __shared__ float As[K1_BK][K1_BM + 1];
  __shared__ float Bs[K1_BK][K1_BN + 1];
  const int tid  = threadIdx.x;
  const int row0 = blockIdx.x * K1_BM;
  const int col0 = blockIdx.y * K1_BN;
  const int tc = (tid & 15) * 4;
  const int tr = (tid >> 4) * 2;
  float acc[2][4] = {};

  for (int k0 = 0; k0 < F_; k0 += K1_BK) {
    {
      const int r = tid >> 3, c = (tid & 7) * 4;
      const float4 v = *(const float4*)&x[(row0 + r) * F_ + k0 + c];
      As[c + 0][r] = v.x; As[c + 1][r] = v.y; As[c + 2][r] = v.z; As[c + 3][r] = v.w;
    }
#pragma unroll
    for (int i0 = 0; i0 < 2; ++i0) {
      const int i = tid + i0 * 256;
      const int g = i >> 3, c = (i & 7) * 4;
      const float4 v = *(const float4*)&Uw[(col0 + g) * F_ + k0 + c];
      Bs[c + 0][g] = v.x; Bs[c + 1][g] = v.y; Bs[c + 2][g] = v.z; Bs[c + 3][g] = v.w;
    }
    __syncthreads();
#pragma unroll
    for (int k = 0; k < K1_BK; ++k) {
      const float a0 = As[k][tr], a1 = As[k][tr + 1];
      const float b0 = Bs[k][tc + 0], b1 = Bs[k][tc + 1];
      const float b2 = Bs[k][tc + 2], b3 = Bs[k][tc + 3];
      acc[0][0] = fmaf(a0, b0, acc[0][0]);
      acc[0][1] = fmaf(a0, b1, acc[0][1]);
      acc[0][2] = fmaf(a0, b2, acc[0][2]);
      acc[0][3] = fmaf(a0, b3, acc[0][3]);
      acc[1][0] = fmaf(a1, b0, acc[1][0]);
      acc[1][1] = fmaf(a1, b1, acc[1][1]);
      acc[1][2] = fmaf(a1, b2, acc[1][2]);
      acc[1][3] = fmaf(a1, b3, acc[1][3]);
    }
    __syncthreads();
  }
#pragma unroll
  for (int r = 0; r < 2; ++r) {
    float4 o;
    o.x = (acc[r][0] + Ub[col0 + tc + 0]) * LOG2E2;
    o.y = (acc[r][1] + Ub[col0 + tc + 1]) * LOG2E2;
    o.z = (acc[r][2] + Ub[col0 + tc + 2]) * LOG2E2;
    o.w = (acc[r][3] + Ub[col0 + tc + 3]) * LOG2E2;
    *(float4*)&u[(row0 + tr + r) * F_ + col0 + tc] = o;
  }
}

// ---------------------------------------------------------------------------
// K2 v5: register-resident hot loop (NO memory ops inside).
// Grid (mg=4, ns=8, b=8), 512 threads = 8 waves.
//   wave  = f-chunk fc (32 f each, 8*32 = 256)
//   lane  = m offset within mg's 64 m
//   block = 16 n (n0 = ns*16)
// Per thread: y[m][fc-chunk] (8 float4) + Ww chunk (8 float4, wave-uniform ->
// SGPR) in registers; u rows are wave-uniform s_loads.
// S[n][m] = sum_f Ww[f] * rcp(exp2(u2[n][f]*y[m][f]) + 1)
//   where u2 = (x.Uw^T + Ub)*2log2e.  alpha = Wsum - 2S (monotone decreasing)
//   -> reduce MIN of S; Wsum cancels in softmax (shift-invariant).
// Cross-fc sum via one LDS round; then rowmin (over m, shfl) and colmin
// (over n, LDS) partials.
// ---------------------------------------------------------------------------
__global__ __launch_bounds__(512) void k2_alpha(const float* __restrict__ u,
                                                const float* __restrict__ y,
                                                const float* __restrict__ Ww,
                                                float* __restrict__ rminp,
                                                float* __restrict__ cminp) {
  __shared__ float red[16][8][64];   // 32 KB  [n][fc][m]
  __shared__ float cred[8][64];      //  2 KB

  const int tid  = threadIdx.x;
  const int lane = tid & 63;
  const int wv   = tid >> 6;
  const int fc   = __builtin_amdgcn_readfirstlane(wv);
  const int mg = blockIdx.x, ns = blockIdx.y, b = blockIdx.z;
  const int m0 = mg * 64, n0 = ns * 16;

  // one-time register staging
  float4 yv[8], wwv[8];
  {
    const float* yr = y + ((size_t)(b * M_ + m0 + lane)) * F_ + fc * 32;
    const float* wr = Ww + fc * 32;
#pragma unroll
    for (int j = 0; j < 8; ++j) {
      yv[j]  = *(const float4*)&yr[4 * j];   // per-lane (transposed, one-time)
      wwv[j] = *(const float4*)&wr[4 * j];   // wave-uniform -> SGPR
    }
  }

  float part[16];
  const float* ub = u + ((size_t)(b * N_ + n0)) * F_ + fc * 32;
#pragma unroll
  for (int n = 0; n < 16; ++n) {
    const float* ur = ub + n * F_;           // wave-uniform -> s_load
    float s0 = 0.f, s1 = 0.f;
#pragma unroll
    for (int j = 0; j < 8; ++j) {
      const float4 uv = *(const float4*)&ur[4 * j];
      s0 = fmaf(wwv[j].x, __builtin_amdgcn_rcpf(__builtin_amdgcn_exp2f(uv.x * yv[j].x) + 1.f), s0);
      s1 = fmaf(wwv[j].y, __builtin_amdgcn_rcpf(__builtin_amdgcn_exp2f(uv.y * yv[j].y) + 1.f), s1);
      s0 = fmaf(wwv[j].z, __builtin_amdgcn_rcpf(__builtin_amdgcn_exp2f(uv.z * yv[j].z) + 1.f), s0);
      s1 = fmaf(wwv[j].w, __builtin_amdgcn_rcpf(__builtin_amdgcn_exp2f(uv.w * yv[j].w) + 1.f), s1);
    }
    part[n] = s0 + s1;
  }

  // ---- sum partials across the 8 f-chunk waves ----
#pragma unroll
  for (int n = 0; n < 16; ++n) red[n][wv][lane] = part[n];
  __syncthreads();

  const int na = wv * 2, nb = wv * 2 + 1;    // each wave finalizes 2 n's
  float Sa = 0.f, Sb = 0.f;
#pragma unroll
  for (int k = 0; k < 8; ++k) { Sa += red[na][k][lane]; Sb += red[nb][k][lane]; }

  // row (over this block's 64 m) MIN of S  -> partial per (n, mg)
  float ra = Sa, rb = Sb;
#pragma unroll
  for (int s = 32; s; s >>= 1) {
    ra = fminf(ra, __shfl_xor(ra, s));
    rb = fminf(rb, __shfl_xor(rb, s));
  }
  if (lane == 0) {
    rminp[((size_t)b * 4 + mg) * N_ + n0 + na] = ra;
    rminp[((size_t)b * 4 + mg) * N_ + n0 + nb] = rb;
  }

  // col (over this block's 16 n) MIN of S -> partial per (ns, m)
  cred[wv][lane] = fminf(Sa, Sb);
  __syncthreads();
  if (wv == 0) {
    float c = cred[0][lane];
#pragma unroll
    for (int k = 1; k < 8; ++k) c = fminf(c, cred[k][lane]);
    cminp[((size_t)b * 8 + ns) * M_ + m0 + lane] = c;
  }
}

// ---------------------------------------------------------------------------
// K3: per-batch finish. 1024 threads. Softmax inputs are -2 * min-partials.
// ---------------------------------------------------------------------------
__global__ __launch_bounds__(1024) void k3_final(const float* __restrict__ x,
                                                 const float* __restrict__ y,
                                                 const float* __restrict__ rminp,
                                                 const float* __restrict__ cminp,
                                                 float* __restrict__ out) {
  const int b = blockIdx.x;
  const int tid = threadIdx.x;
  const int wv = tid >> 6;
  __shared__ float xw[N_];
  __shared__ float yw[M_];
  __shared__ float red[16];
  __shared__ float part[4][256];

  // ---- x attention: softmax over n of (-2 * min_m S) ----
  float rv = -INFINITY;
  if (tid < N_) {
    float v = INFINITY;
#pragma unroll
    for (int mg = 0; mg < 4; ++mg)
      v = fminf(v, rminp[((size_t)b * 4 + mg) * N_ + tid]);
    rv = -2.f * v;
  }
  float m1 = rv;
#pragma unroll
  for (int s = 32; s; s >>= 1) m1 = fmaxf(m1, __shfl_xor(m1, s));
  if ((tid & 63) == 0) red[wv] = m1;
  __syncthreads();
  m1 = red[0];
#pragma unroll
  for (int w = 1; w < 16; ++w) m1 = fmaxf(m1, red[w]);
  __syncthreads();
  const float e1 = (tid < N_) ? __expf(rv - m1) : 0.f;
  float s1 = e1;
#pragma unroll
  for (int s = 32; s; s >>= 1) s1 += __shfl_xor(s1, s);
  if ((tid & 63) == 0) red[wv] = s1;
  __syncthreads();
  s1 = 0.f;
#pragma unroll
  for (int w = 0; w < 16; ++w) s1 += red[w];
  if (tid < N_) xw[tid] = e1 / s1;
  __syncthreads();

  // ---- y attention: softmax over m of (-2 * min_n S) ----
  float cv = -INFINITY;
  if (tid < M_) {
    float c = INFINITY;
#pragma unroll
    for (int ns = 0; ns < 8; ++ns)
      c = fminf(c, cminp[((size_t)b * 8 + ns) * M_ + tid]);
    cv = -2.f * c;
  }
  float m2 = cv;
#pragma unroll
  for (int s = 32; s; s >>= 1) m2 = fmaxf(m2, __shfl_xor(m2, s));
  if ((tid & 63) == 0) red[wv] = m2;
  __syncthreads();
  m2 = red[0];
#pragma unroll
  for (int w = 1; w < 16; ++w) m2 = fmaxf(m2, red[w]);
  __syncthreads();
  const float e2 = (tid < M_) ? __expf(cv - m2) : 0.f;
  float s2 = e2;
#pragma unroll
  for (int s = 32; s; s >>= 1) s2 += __shfl_xor(s2, s);
  if ((tid & 63) == 0) red[wv] = s2;
  __syncthreads();
  s2 = 0.f;
#pragma unroll
  for (int w = 0; w < 16; ++w) s2 += red[w];
  if (tid < M_) yw[tid] = e2 / s2;
  __syncthreads();

  // ---- pooled outputs, 4-way split over sum dimension ----
  const int q = tid >> 8;      // 0..3
  const int f = tid & 255;

  float accx = 0.f;
#pragma unroll 4
  for (int n = q; n < N_; n += 4)
    accx = fmaf(xw[n], x[(size_t)(b * N_ + n) * F_ + f], accx);
  part[q][f] = accx;
  __syncthreads();
  if (tid < 256)
    out[b * (2 * F_) + f] = part[0][f] + part[1][f] + part[2][f] + part[3][f];
  __syncthreads();

  float accy = 0.f;
#pragma unroll 4
  for (int m = q; m < M_; m += 4)
    accy = fmaf(yw[m], y[(size_t)(b * M_ + m) * F_ + f], accy);
  part[q][f] = accy;
  __syncthreads();
  if (tid < 256)
    out[b * (2 * F_) + F_ + f] = part[0][f] + part[1][f] + part[2][f] + part[3][f];
}

// ---------------------------------------------------------------------------
extern "C" void kernel_launch(void* const* d_in, const int* in_sizes, int n_in,
                              void* d_out, int out_size, void* d_ws, size_t ws_size,
                              hipStream_t stream) {
  (void)in_sizes; (void)n_in; (void)out_size; (void)ws_size;
  const float* x  = (const float*)d_in[0];
  const float* y  = (const float*)d_in[1];
  const float* Uw = (const float*)d_in[2];
  const float* Ub = (const float*)d_in[3];
  const float* Ww = (const float*)d_in[4];
  // d_in[5] (W_b) unused: max/softmax pipeline is shift-invariant.

  float* u     = (float*)d_ws;                 // [B][N][F]    262144 f
  float* rminp = u + B_ * N_ * F_;             // [B][4][N]      4096 f
  float* cminp = rminp + B_ * 4 * N_;          // [B][8][M]     16384 f
  float* out   = (float*)d_out;

  k1_gemm<<<dim3((B_ * N_) / K1_BM, F_ / K1_BN), 256, 0, stream>>>(x, Uw, Ub, u);
  k2_alpha<<<dim3(4, 8, B_), 512, 0, stream>>>(u, y, Ww, rminp, cminp);
  k3_final<<<dim3(B_), 1024, 0, stream>>>(x, y, rminp, cminp, out);
}